// Round 1
// baseline (185.571 us; speedup 1.0000x reference)
//
#include <hip/hip_runtime.h>
#include <hip/hip_bf16.h>

// Problem constants
#define N_B   4
#define T_LEN 1024
#define NREF  128
#define H     4
#define KQ    128
#define LD    128
#define HKQ   (H*KQ)   // 512
#define HLD   (H*LD)   // 512

__device__ __forceinline__ float time_emb_elem(float t, int c) {
    // c in [0,64): z[2i]=sin(48*t*div_i), z[2i+1]=cos(48*t*div_i)
    // div_i = exp(-(2i)*ln(10)/64)
    int i = c >> 1;
    float div = __expf(-(float)(2 * i) * (2.302585093f / 64.0f));
    float ang = 48.0f * t * div;
    return (c & 1) ? __cosf(ang) : __sinf(ang);
}

// hq[q, j] = q_in[q,:] @ Wq[:, j] + bq[j]   (batch-independent)
// grid 128 (q), block 128
__global__ void hq_kernel(const float* __restrict__ emb0, const float* __restrict__ emb1,
                          const float* __restrict__ Wq, const float* __restrict__ bq,
                          float* __restrict__ hq) {
    __shared__ float qin[KQ];
    int q = blockIdx.x;
    int tid = threadIdx.x;
    if (tid < 64) {
        float t = (float)q / 127.0f;  // linspace(0,1,128)
        qin[tid] = time_emb_elem(t, tid);
    } else if (tid < 96) {
        qin[tid] = emb0[100 * 32 + (tid - 64)];   // null class row
    } else {
        qin[tid] = emb1[50 * 32 + (tid - 96)];
    }
    __syncthreads();
    #pragma unroll
    for (int r = 0; r < 4; ++r) {
        int j = tid + r * 128;
        float acc = bq[j];
        #pragma unroll 8
        for (int i = 0; i < KQ; ++i) acc += qin[i] * Wq[i * HKQ + j];
        hq[q * HKQ + j] = acc;
    }
}

// hk[bt, j] = k_in[bt,:] @ Wk[:, j] + bk[j]; 8 timesteps per block to amortize Wk
// grid N*T/8 = 512, block 256
__global__ void hk_kernel(const float* __restrict__ ts, const int* __restrict__ ys0,
                          const int* __restrict__ ys1,
                          const float* __restrict__ emb0, const float* __restrict__ emb1,
                          const float* __restrict__ Wk, const float* __restrict__ bk,
                          float* __restrict__ hk) {
    __shared__ float kin[8][KQ];
    int tid = threadIdx.x;
    int base = blockIdx.x * 8;  // flat (b*T + t) base
    for (int e = tid; e < 8 * KQ; e += 256) {
        int tt = e >> 7, c = e & 127;
        int bt = base + tt;
        float v;
        if (c < 64) {
            v = time_emb_elem(ts[bt], c);
        } else if (c < 96) {
            v = emb0[ys0[bt] * 32 + (c - 64)];
        } else {
            v = emb1[ys1[bt] * 32 + (c - 96)];
        }
        kin[tt][c] = v;
    }
    __syncthreads();
    int j0 = tid, j1 = tid + 256;
    float acc[8][2];
    #pragma unroll
    for (int tt = 0; tt < 8; ++tt) { acc[tt][0] = bk[j0]; acc[tt][1] = bk[j1]; }
    for (int i = 0; i < KQ; ++i) {
        float w0 = Wk[i * HKQ + j0], w1 = Wk[i * HKQ + j1];
        #pragma unroll
        for (int tt = 0; tt < 8; ++tt) {
            float k = kin[tt][i];
            acc[tt][0] = fmaf(k, w0, acc[tt][0]);
            acc[tt][1] = fmaf(k, w1, acc[tt][1]);
        }
    }
    #pragma unroll
    for (int tt = 0; tt < 8; ++tt) {
        hk[(base + tt) * HKQ + j0] = acc[tt][0];
        hk[(base + tt) * HKQ + j1] = acc[tt][1];
    }
}

// Attention for one (b, h, 8-query tile): scores -> softmax -> @x
// grid (NREF/8=16, H=4, N=4), block 256
__global__ void attn_kernel(const float* __restrict__ hq, const float* __restrict__ hk,
                            const float* __restrict__ x, float* __restrict__ att) {
    __shared__ float hql[8][KQ];
    __shared__ float hkl[32][KQ + 1];   // +1 pad: kills 32-way bank conflict
    __shared__ float sc[8][T_LEN];
    int tid = threadIdx.x;
    int qt = blockIdx.x, h = blockIdx.y, b = blockIdx.z;
    int q0 = qt * 8;

    for (int e = tid; e < 8 * KQ; e += 256) {
        int qi = e >> 7, d = e & 127;
        hql[qi][d] = hq[(q0 + qi) * HKQ + h * KQ + d];
    }

    const float scale = 0.08838834764831845f;  // 1/sqrt(128)
    int qi = tid >> 5;       // 0..7
    int lane32 = tid & 31;
    for (int t0 = 0; t0 < T_LEN; t0 += 32) {
        __syncthreads();  // hql ready (first iter) / hkl consumed (later iters)
        for (int e = tid; e < 32 * KQ; e += 256) {
            int ttt = e >> 7, d = e & 127;
            hkl[ttt][d] = hk[(b * T_LEN + t0 + ttt) * HKQ + h * KQ + d];
        }
        __syncthreads();
        float acc = 0.f;
        #pragma unroll 8
        for (int d = 0; d < KQ; ++d) acc = fmaf(hql[qi][d], hkl[lane32][d], acc);
        sc[qi][t0 + lane32] = acc * scale;
    }
    __syncthreads();

    // softmax per row qi (32 threads per row, within one 64-lane wave half)
    float m = -1e30f;
    for (int t = lane32; t < T_LEN; t += 32) m = fmaxf(m, sc[qi][t]);
    #pragma unroll
    for (int o = 16; o >= 1; o >>= 1) m = fmaxf(m, __shfl_xor(m, o));
    float s = 0.f;
    for (int t = lane32; t < T_LEN; t += 32) {
        float e = __expf(sc[qi][t] - m);
        sc[qi][t] = e;
        s += e;
    }
    #pragma unroll
    for (int o = 16; o >= 1; o >>= 1) s += __shfl_xor(s, o);
    float inv = 1.0f / s;
    for (int t = lane32; t < T_LEN; t += 32) sc[qi][t] *= inv;
    __syncthreads();

    // PV: out[qi][v] = sum_t p[qi][t] * x[b,t,v]; coalesced x reads
    int v = tid & 127, qg = tid >> 7;  // qg in {0,1} -> rows qg*4..qg*4+3
    float out[4] = {0.f, 0.f, 0.f, 0.f};
    for (int t = 0; t < T_LEN; ++t) {
        float xv = x[(b * T_LEN + t) * LD + v];
        #pragma unroll
        for (int r = 0; r < 4; ++r) out[r] = fmaf(sc[qg * 4 + r][t], xv, out[r]);
    }
    #pragma unroll
    for (int r = 0; r < 4; ++r) {
        int qq = q0 + qg * 4 + r;
        att[(b * NREF + qq) * HLD + h * LD + v] = out[r];
    }
}

// out[row, j] = att[row,:] @ Wo[:, j] + bo[j]
// grid N*NREF = 512, block 128
__global__ void out_kernel(const float* __restrict__ att, const float* __restrict__ Wo,
                           const float* __restrict__ bo, float* __restrict__ out) {
    __shared__ float a[HLD];
    int row = blockIdx.x;
    int tid = threadIdx.x;
    for (int e = tid; e < HLD; e += 128) a[e] = att[row * HLD + e];
    __syncthreads();
    float acc = bo[tid];
    #pragma unroll 8
    for (int i = 0; i < HLD; ++i) acc = fmaf(a[i], Wo[i * LD + tid], acc);
    out[row * LD + tid] = acc;
}

extern "C" void kernel_launch(void* const* d_in, const int* in_sizes, int n_in,
                              void* d_out, int out_size, void* d_ws, size_t ws_size,
                              hipStream_t stream) {
    const float* ts   = (const float*)d_in[0];
    const int*   ys0  = (const int*)d_in[1];
    const int*   ys1  = (const int*)d_in[2];
    const float* x    = (const float*)d_in[3];
    const float* emb0 = (const float*)d_in[4];
    const float* emb1 = (const float*)d_in[5];
    const float* Wq   = (const float*)d_in[6];
    const float* bq   = (const float*)d_in[7];
    const float* Wk   = (const float*)d_in[8];
    const float* bk   = (const float*)d_in[9];
    const float* Wo   = (const float*)d_in[10];
    const float* bo   = (const float*)d_in[11];
    float* out = (float*)d_out;

    float* ws = (float*)d_ws;
    float* hq  = ws;                       // 128*512          = 65536 floats
    float* hk  = hq + NREF * HKQ;          // 4*1024*512       = 2097152 floats
    float* att = hk + N_B * T_LEN * HKQ;   // 4*128*512        = 262144 floats

    hipLaunchKernelGGL(hq_kernel, dim3(NREF), dim3(128), 0, stream, emb0, emb1, Wq, bq, hq);
    hipLaunchKernelGGL(hk_kernel, dim3(N_B * T_LEN / 8), dim3(256), 0, stream,
                       ts, ys0, ys1, emb0, emb1, Wk, bk, hk);
    hipLaunchKernelGGL(attn_kernel, dim3(NREF / 8, H, N_B), dim3(256), 0, stream, hq, hk, x, att);
    hipLaunchKernelGGL(out_kernel, dim3(N_B * NREF), dim3(128), 0, stream, att, Wo, bo, out);
}

// Round 2
// 88.675 us; speedup vs baseline: 2.0927x; 2.0927x over previous
//
#include <hip/hip_runtime.h>
#include <hip/hip_bf16.h>

#define N_B   4
#define T_LEN 1024
#define NREF  128
#define H     4
#define KQ    128
#define LD    128
#define HKQ   512
#define HLD   512
#define TC    4       // number of T chunks
#define TCHUNK 256    // keys per chunk

__device__ __forceinline__ float time_emb_elem(float t, int c) {
    // c in [0,64): z[2i]=sin(48*t*div_i), z[2i+1]=cos(48*t*div_i)
    int i = c >> 1;
    float div = __expf(-(float)(2 * i) * (2.302585093f / 64.0f));
    float ang = 48.0f * t * div;
    return (c & 1) ? __cosf(ang) : __sinf(ang);
}

// hq[q, h*KQ+j] = q_in[q,:] @ Wq[:, h*KQ+j] + bq   grid (8 qt, 4 h), block 256
__global__ __launch_bounds__(256) void hq_kernel(const float* __restrict__ emb0,
                                                 const float* __restrict__ emb1,
                                                 const float* __restrict__ Wq,
                                                 const float* __restrict__ bq,
                                                 float* __restrict__ hq) {
    __shared__ float qinT[KQ][20];
    int tid = threadIdx.x;
    int q0 = blockIdx.x * 16, h = blockIdx.y;
    for (int e = tid; e < 16 * KQ; e += 256) {
        int i = e & 127, q = e >> 7;
        float t = (float)(q0 + q) / 127.0f;   // linspace(0,1,128)
        float v;
        if (i < 64)      v = time_emb_elem(t, i);
        else if (i < 96) v = emb0[100 * 32 + (i - 64)];
        else             v = emb1[50 * 32 + (i - 96)];
        qinT[i][q] = v;
    }
    __syncthreads();
    int j = tid & 127, qp = tid >> 7;   // q = qp*8 + r
    int col = h * KQ + j;
    float acc[8];
    #pragma unroll
    for (int r = 0; r < 8; ++r) acc[r] = 0.f;
    for (int i = 0; i < KQ; ++i) {
        float w = Wq[i * HKQ + col];
        #pragma unroll
        for (int r = 0; r < 8; ++r) acc[r] = fmaf(qinT[i][qp * 8 + r], w, acc[r]);
    }
    float b = bq[col];
    #pragma unroll
    for (int r = 0; r < 8; ++r) hq[(size_t)(q0 + qp * 8 + r) * HKQ + col] = acc[r] + b;
}

// hk[bt, j] = k_in[bt,:] @ Wk[:, j] + bk[j]   grid 256 (16 t each), block 512
__global__ __launch_bounds__(512) void hk_kernel(const float* __restrict__ ts,
                                                 const int* __restrict__ ys0,
                                                 const int* __restrict__ ys1,
                                                 const float* __restrict__ emb0,
                                                 const float* __restrict__ emb1,
                                                 const float* __restrict__ Wk,
                                                 const float* __restrict__ bk,
                                                 float* __restrict__ hk) {
    __shared__ float kinT[KQ][20];
    int tid = threadIdx.x;
    int base = blockIdx.x * 16;
    for (int e = tid; e < 16 * KQ; e += 512) {
        int i = e & 127, tt = e >> 7;
        int bt = base + tt;
        float v;
        if (i < 64)      v = time_emb_elem(ts[bt], i);
        else if (i < 96) v = emb0[ys0[bt] * 32 + (i - 64)];
        else             v = emb1[ys1[bt] * 32 + (i - 96)];
        kinT[i][tt] = v;
    }
    __syncthreads();
    int j = tid;
    float acc[16];
    #pragma unroll
    for (int tt = 0; tt < 16; ++tt) acc[tt] = 0.f;
    for (int i = 0; i < KQ; ++i) {
        float w = Wk[i * HKQ + j];
        float4 k0 = *(const float4*)&kinT[i][0];
        float4 k1 = *(const float4*)&kinT[i][4];
        float4 k2 = *(const float4*)&kinT[i][8];
        float4 k3 = *(const float4*)&kinT[i][12];
        acc[0]  = fmaf(k0.x, w, acc[0]);  acc[1]  = fmaf(k0.y, w, acc[1]);
        acc[2]  = fmaf(k0.z, w, acc[2]);  acc[3]  = fmaf(k0.w, w, acc[3]);
        acc[4]  = fmaf(k1.x, w, acc[4]);  acc[5]  = fmaf(k1.y, w, acc[5]);
        acc[6]  = fmaf(k1.z, w, acc[6]);  acc[7]  = fmaf(k1.w, w, acc[7]);
        acc[8]  = fmaf(k2.x, w, acc[8]);  acc[9]  = fmaf(k2.y, w, acc[9]);
        acc[10] = fmaf(k2.z, w, acc[10]); acc[11] = fmaf(k2.w, w, acc[11]);
        acc[12] = fmaf(k3.x, w, acc[12]); acc[13] = fmaf(k3.y, w, acc[13]);
        acc[14] = fmaf(k3.z, w, acc[14]); acc[15] = fmaf(k3.w, w, acc[15]);
    }
    float b = bk[j];
    #pragma unroll
    for (int tt = 0; tt < 16; ++tt) hk[(size_t)(base + tt) * HKQ + j] = acc[tt] + b;
}

// Partial attention: one (16q, h, b, 256-key chunk) per block; writes m_c, s_c, pout_c
// grid (8 qt, 16 = h + 4*tc, 4 b), block 256
__global__ __launch_bounds__(256) void attn_part(const float* __restrict__ hq,
                                                 const float* __restrict__ hk,
                                                 const float* __restrict__ x,
                                                 float* __restrict__ pm,
                                                 float* __restrict__ ps,
                                                 float* __restrict__ pout) {
    __shared__ float hkl[TCHUNK][20];   // 16-d slab of 256 keys, stride 20 = bank-optimal
    __shared__ float hql[16][20];
    __shared__ float sc[16][260];
    int tid = threadIdx.x;
    int qt = blockIdx.x, h = blockIdx.y & 3, tc = blockIdx.y >> 2, b = blockIdx.z;
    int q0 = qt * 16, t0 = tc * TCHUNK;

    float acc[8][2];
    #pragma unroll
    for (int r = 0; r < 8; ++r) { acc[r][0] = 0.f; acc[r][1] = 0.f; }
    int qg = tid >> 7;      // 0..1 -> q = qg*8 + r
    int kg = tid & 127;     // keys kg, kg+128

    for (int slab = 0; slab < 8; ++slab) {
        int d0 = slab * 16;
        __syncthreads();
        {   int q = tid >> 4, dd = tid & 15;
            hql[q][dd] = hq[(size_t)(q0 + q) * HKQ + h * KQ + d0 + dd]; }
        {   const float* src = hk + (size_t)(b * T_LEN + t0 + tid) * HKQ + h * KQ + d0;
            float4 v0 = *(const float4*)(src);
            float4 v1 = *(const float4*)(src + 4);
            float4 v2 = *(const float4*)(src + 8);
            float4 v3 = *(const float4*)(src + 12);
            *(float4*)&hkl[tid][0]  = v0;
            *(float4*)&hkl[tid][4]  = v1;
            *(float4*)&hkl[tid][8]  = v2;
            *(float4*)&hkl[tid][12] = v3; }
        __syncthreads();
        #pragma unroll
        for (int d4 = 0; d4 < 4; ++d4) {
            float4 ka = *(const float4*)&hkl[kg][d4 * 4];
            float4 kb = *(const float4*)&hkl[kg + 128][d4 * 4];
            #pragma unroll
            for (int r = 0; r < 8; ++r) {
                float4 qv = *(const float4*)&hql[qg * 8 + r][d4 * 4];
                acc[r][0] = fmaf(qv.x, ka.x, acc[r][0]);
                acc[r][0] = fmaf(qv.y, ka.y, acc[r][0]);
                acc[r][0] = fmaf(qv.z, ka.z, acc[r][0]);
                acc[r][0] = fmaf(qv.w, ka.w, acc[r][0]);
                acc[r][1] = fmaf(qv.x, kb.x, acc[r][1]);
                acc[r][1] = fmaf(qv.y, kb.y, acc[r][1]);
                acc[r][1] = fmaf(qv.z, kb.z, acc[r][1]);
                acc[r][1] = fmaf(qv.w, kb.w, acc[r][1]);
            }
        }
    }
    const float scale = 0.08838834764831845f;  // 1/sqrt(128)
    #pragma unroll
    for (int r = 0; r < 8; ++r) {
        sc[qg * 8 + r][kg]       = acc[r][0] * scale;
        sc[qg * 8 + r][kg + 128] = acc[r][1] * scale;
    }
    __syncthreads();

    // partial softmax per row (16 lanes per row)
    int row = tid >> 4, l16 = tid & 15;
    float m = -1e30f;
    for (int t = l16; t < TCHUNK; t += 16) m = fmaxf(m, sc[row][t]);
    #pragma unroll
    for (int o = 8; o >= 1; o >>= 1) m = fmaxf(m, __shfl_xor(m, o, 16));
    float s = 0.f;
    for (int t = l16; t < TCHUNK; t += 16) {
        float e = __expf(sc[row][t] - m);
        sc[row][t] = e;
        s += e;
    }
    #pragma unroll
    for (int o = 8; o >= 1; o >>= 1) s += __shfl_xor(s, o, 16);
    int pbase = ((b * H + h) * TC + tc) * NREF + q0;
    if (l16 == 0) { pm[pbase + row] = m; ps[pbase + row] = s; }
    __syncthreads();

    // partial PV: pout[q][v] = sum_t e^(sc-m) * x[b,t0+t,v]
    int v4 = tid & 31, qp = tid >> 5;   // rows qp*2, qp*2+1
    float o0[4] = {0.f, 0.f, 0.f, 0.f}, o1[4] = {0.f, 0.f, 0.f, 0.f};
    const float* xb = x + (size_t)(b * T_LEN + t0) * LD + v4 * 4;
    for (int t = 0; t < TCHUNK; ++t) {
        float4 xv = *(const float4*)(xb + (size_t)t * LD);
        float p0 = sc[qp * 2][t], p1 = sc[qp * 2 + 1][t];
        o0[0] = fmaf(p0, xv.x, o0[0]); o0[1] = fmaf(p0, xv.y, o0[1]);
        o0[2] = fmaf(p0, xv.z, o0[2]); o0[3] = fmaf(p0, xv.w, o0[3]);
        o1[0] = fmaf(p1, xv.x, o1[0]); o1[1] = fmaf(p1, xv.y, o1[1]);
        o1[2] = fmaf(p1, xv.z, o1[2]); o1[3] = fmaf(p1, xv.w, o1[3]);
    }
    size_t ob = ((size_t)pbase + qp * 2) * LD + v4 * 4;
    *(float4*)&pout[ob]      = make_float4(o0[0], o0[1], o0[2], o0[3]);
    *(float4*)&pout[ob + LD] = make_float4(o1[0], o1[1], o1[2], o1[3]);
}

// Combine 4 chunks + output projection. grid (32 qt4, 4 b), block 256
__global__ __launch_bounds__(256) void outc_kernel(const float* __restrict__ pm,
                                                   const float* __restrict__ ps,
                                                   const float* __restrict__ pout,
                                                   const float* __restrict__ Wo,
                                                   const float* __restrict__ bo,
                                                   float* __restrict__ out) {
    __shared__ float attl[4][516];
    int tid = threadIdx.x;
    int q0 = blockIdx.x * 4, b = blockIdx.y;
    for (int u = 0; u < 8; ++u) {
        int e = u * 256 + tid;
        int r = e >> 9, hv = e & 511;
        int h = hv >> 7, v = hv & 127;
        int pb = ((b * H + h) * TC) * NREF + q0 + r;
        float m0 = pm[pb], m1 = pm[pb + NREF], m2 = pm[pb + 2 * NREF], m3 = pm[pb + 3 * NREF];
        float m = fmaxf(fmaxf(m0, m1), fmaxf(m2, m3));
        float w0 = __expf(m0 - m), w1 = __expf(m1 - m), w2 = __expf(m2 - m), w3 = __expf(m3 - m);
        float den = w0 * ps[pb] + w1 * ps[pb + NREF] + w2 * ps[pb + 2 * NREF] + w3 * ps[pb + 3 * NREF];
        size_t po = (size_t)pb * LD + v;
        float num = w0 * pout[po]
                  + w1 * pout[po + (size_t)NREF * LD]
                  + w2 * pout[po + 2 * (size_t)NREF * LD]
                  + w3 * pout[po + 3 * (size_t)NREF * LD];
        attl[r][hv] = num / den;
    }
    __syncthreads();
    int j = tid & 127, rp = tid >> 7;   // rows rp, rp+2
    float a0 = 0.f, a1 = 0.f;
    for (int i = 0; i < HLD; ++i) {
        float w = Wo[i * LD + j];
        a0 = fmaf(attl[rp][i], w, a0);
        a1 = fmaf(attl[rp + 2][i], w, a1);
    }
    float bb = bo[j];
    out[((size_t)b * NREF + q0 + rp) * LD + j]     = a0 + bb;
    out[((size_t)b * NREF + q0 + rp + 2) * LD + j] = a1 + bb;
}

extern "C" void kernel_launch(void* const* d_in, const int* in_sizes, int n_in,
                              void* d_out, int out_size, void* d_ws, size_t ws_size,
                              hipStream_t stream) {
    const float* ts   = (const float*)d_in[0];
    const int*   ys0  = (const int*)d_in[1];
    const int*   ys1  = (const int*)d_in[2];
    const float* x    = (const float*)d_in[3];
    const float* emb0 = (const float*)d_in[4];
    const float* emb1 = (const float*)d_in[5];
    const float* Wq   = (const float*)d_in[6];
    const float* bq   = (const float*)d_in[7];
    const float* Wk   = (const float*)d_in[8];
    const float* bk   = (const float*)d_in[9];
    const float* Wo   = (const float*)d_in[10];
    const float* bo   = (const float*)d_in[11];
    float* out = (float*)d_out;

    float* ws   = (float*)d_ws;
    float* hq   = ws;                     // 128*512            = 65536
    float* hk   = hq + 65536;             // 4096*512           = 2097152
    float* pm   = hk + 2097152;           // 4*4*4*128          = 8192
    float* ps   = pm + 8192;              // 8192
    float* pout = ps + 8192;              // 4*4*4*128*128      = 1048576
    // total 3,227,648 floats = 12.9 MB

    hipLaunchKernelGGL(hq_kernel, dim3(8, 4), dim3(256), 0, stream, emb0, emb1, Wq, bq, hq);
    hipLaunchKernelGGL(hk_kernel, dim3(256), dim3(512), 0, stream,
                       ts, ys0, ys1, emb0, emb1, Wk, bk, hk);
    hipLaunchKernelGGL(attn_part, dim3(8, 16, 4), dim3(256), 0, stream, hq, hk, x, pm, ps, pout);
    hipLaunchKernelGGL(outc_kernel, dim3(32, 4), dim3(256), 0, stream, pm, ps, pout, Wo, bo, out);
}

// Round 3
// 70.888 us; speedup vs baseline: 2.6178x; 1.2509x over previous
//
#include <hip/hip_runtime.h>
#include <hip/hip_bf16.h>

#define N_B   4
#define T_LEN 1024
#define NREF  128
#define H     4
#define KQ    128
#define LD    128
#define HKQ   512
#define HLD   512
#define TC    4       // number of T chunks
#define TCHUNK 256    // keys per chunk

typedef __attribute__((ext_vector_type(8))) short bf16x8;   // 8 bf16 = 4 VGPRs
typedef __attribute__((ext_vector_type(4))) float f32x4;

__device__ __forceinline__ float time_emb_elem(float t, int c) {
    int i = c >> 1;
    float div = __expf(-(float)(2 * i) * (2.302585093f / 64.0f));
    float ang = 48.0f * t * div;
    return (c & 1) ? __cosf(ang) : __sinf(ang);
}

// hq[q, h*KQ+j] (bf16) = q_in[q,:] @ Wq[:, h*KQ+j] + bq   grid (8 qt, 4 h), block 256
__global__ __launch_bounds__(256) void hq_kernel(const float* __restrict__ emb0,
                                                 const float* __restrict__ emb1,
                                                 const float* __restrict__ Wq,
                                                 const float* __restrict__ bq,
                                                 __hip_bfloat16* __restrict__ hq) {
    __shared__ float qinT[KQ][20];
    int tid = threadIdx.x;
    int q0 = blockIdx.x * 16, h = blockIdx.y;
    for (int e = tid; e < 16 * KQ; e += 256) {
        int i = e & 127, q = e >> 7;
        float t = (float)(q0 + q) / 127.0f;
        float v;
        if (i < 64)      v = time_emb_elem(t, i);
        else if (i < 96) v = emb0[100 * 32 + (i - 64)];
        else             v = emb1[50 * 32 + (i - 96)];
        qinT[i][q] = v;
    }
    __syncthreads();
    int j = tid & 127, qp = tid >> 7;
    int col = h * KQ + j;
    float acc[8];
    #pragma unroll
    for (int r = 0; r < 8; ++r) acc[r] = 0.f;
    for (int i = 0; i < KQ; ++i) {
        float w = Wq[i * HKQ + col];
        #pragma unroll
        for (int r = 0; r < 8; ++r) acc[r] = fmaf(qinT[i][qp * 8 + r], w, acc[r]);
    }
    float b = bq[col];
    #pragma unroll
    for (int r = 0; r < 8; ++r)
        hq[(size_t)(q0 + qp * 8 + r) * HKQ + col] = __float2bfloat16(acc[r] + b);
}

// hk[bt, j] (bf16) = k_in[bt,:] @ Wk[:, j] + bk[j]   grid 256 (16 t each), block 512
__global__ __launch_bounds__(512) void hk_kernel(const float* __restrict__ ts,
                                                 const int* __restrict__ ys0,
                                                 const int* __restrict__ ys1,
                                                 const float* __restrict__ emb0,
                                                 const float* __restrict__ emb1,
                                                 const float* __restrict__ Wk,
                                                 const float* __restrict__ bk,
                                                 __hip_bfloat16* __restrict__ hk) {
    __shared__ float kinT[KQ][20];
    int tid = threadIdx.x;
    int base = blockIdx.x * 16;
    for (int e = tid; e < 16 * KQ; e += 512) {
        int i = e & 127, tt = e >> 7;
        int bt = base + tt;
        float v;
        if (i < 64)      v = time_emb_elem(ts[bt], i);
        else if (i < 96) v = emb0[ys0[bt] * 32 + (i - 64)];
        else             v = emb1[ys1[bt] * 32 + (i - 96)];
        kinT[i][tt] = v;
    }
    __syncthreads();
    int j = tid;
    float acc[16];
    #pragma unroll
    for (int tt = 0; tt < 16; ++tt) acc[tt] = 0.f;
    for (int i = 0; i < KQ; ++i) {
        float w = Wk[i * HKQ + j];
        float4 k0 = *(const float4*)&kinT[i][0];
        float4 k1 = *(const float4*)&kinT[i][4];
        float4 k2 = *(const float4*)&kinT[i][8];
        float4 k3 = *(const float4*)&kinT[i][12];
        acc[0]  = fmaf(k0.x, w, acc[0]);  acc[1]  = fmaf(k0.y, w, acc[1]);
        acc[2]  = fmaf(k0.z, w, acc[2]);  acc[3]  = fmaf(k0.w, w, acc[3]);
        acc[4]  = fmaf(k1.x, w, acc[4]);  acc[5]  = fmaf(k1.y, w, acc[5]);
        acc[6]  = fmaf(k1.z, w, acc[6]);  acc[7]  = fmaf(k1.w, w, acc[7]);
        acc[8]  = fmaf(k2.x, w, acc[8]);  acc[9]  = fmaf(k2.y, w, acc[9]);
        acc[10] = fmaf(k2.z, w, acc[10]); acc[11] = fmaf(k2.w, w, acc[11]);
        acc[12] = fmaf(k3.x, w, acc[12]); acc[13] = fmaf(k3.y, w, acc[13]);
        acc[14] = fmaf(k3.z, w, acc[14]); acc[15] = fmaf(k3.w, w, acc[15]);
    }
    float b = bk[j];
    #pragma unroll
    for (int tt = 0; tt < 16; ++tt)
        hk[(size_t)(base + tt) * HKQ + j] = __float2bfloat16(acc[tt] + b);
}

// x [4][1024][128] f32 -> xT [4][128][1024] bf16.  grid (16 ttile, 4 b), block 256
__global__ __launch_bounds__(256) void xt_kernel(const float* __restrict__ x,
                                                 __hip_bfloat16* __restrict__ xT) {
    __shared__ __hip_bfloat16 tile[64][136];
    int tid = threadIdx.x;
    int b = blockIdx.y, t0 = blockIdx.x * 64;
    for (int e = tid; e < 64 * 32; e += 256) {
        int tt = e >> 5, v4 = e & 31;
        float4 xv = *(const float4*)&x[((size_t)(b * T_LEN + t0 + tt)) * LD + v4 * 4];
        tile[tt][v4 * 4 + 0] = __float2bfloat16(xv.x);
        tile[tt][v4 * 4 + 1] = __float2bfloat16(xv.y);
        tile[tt][v4 * 4 + 2] = __float2bfloat16(xv.z);
        tile[tt][v4 * 4 + 3] = __float2bfloat16(xv.w);
    }
    __syncthreads();
    int v = tid >> 1, th = (tid & 1) * 32;
    for (int i = 0; i < 32; i += 4) {
        ushort4 u;
        u.x = *(unsigned short*)&tile[th + i + 0][v];
        u.y = *(unsigned short*)&tile[th + i + 1][v];
        u.z = *(unsigned short*)&tile[th + i + 2][v];
        u.w = *(unsigned short*)&tile[th + i + 3][v];
        *(ushort4*)&xT[((size_t)b * LD + v) * T_LEN + t0 + th + i] = u;
    }
}

// MFMA partial attention: one (16q, h, 256-key chunk, b) per 4-wave block.
// grid (8 qt, 16 = h + 4*tc, 4 b), block 256
__global__ __launch_bounds__(256) void attn_part(const __hip_bfloat16* __restrict__ hq,
                                                 const __hip_bfloat16* __restrict__ hk,
                                                 const __hip_bfloat16* __restrict__ xT,
                                                 float* __restrict__ pm,
                                                 float* __restrict__ ps,
                                                 float* __restrict__ pout) {
    __shared__ __hip_bfloat16 P_lds[16 * 256];   // XOR-swizzled: elem ^= (q&7)<<3
    __shared__ float red[4][16], red2[4][16];

    int tid = threadIdx.x;
    int wave = tid >> 6, lane = tid & 63;
    int lm = lane & 15, lg = lane >> 4;
    int qt = blockIdx.x, h = blockIdx.y & 3, tc = blockIdx.y >> 2, b = blockIdx.z;
    int q0 = qt * 16, t0 = tc * TCHUNK;

    // ---- scores: wave owns keys [wave*64, wave*64+64), 4 ktiles of 16
    f32x4 sacc[4];
    #pragma unroll
    for (int kt = 0; kt < 4; ++kt) sacc[kt] = f32x4{0.f, 0.f, 0.f, 0.f};

    const __hip_bfloat16* aptr = hq + (size_t)(q0 + lm) * HKQ + h * KQ + lg * 8;
    const __hip_bfloat16* bptr = hk + (size_t)(b * T_LEN + t0 + wave * 64 + lm) * HKQ + h * KQ + lg * 8;
    #pragma unroll
    for (int ks = 0; ks < 4; ++ks) {              // d0 = ks*32
        bf16x8 af = *(const bf16x8*)(aptr + ks * 32);
        #pragma unroll
        for (int kt = 0; kt < 4; ++kt) {
            bf16x8 bfr = *(const bf16x8*)(bptr + (size_t)kt * 16 * HKQ + ks * 32);
            sacc[kt] = __builtin_amdgcn_mfma_f32_16x16x32_bf16(af, bfr, sacc[kt], 0, 0, 0);
        }
    }
    // D layout: reg r -> row q = 4*lg + r, col key = wave*64 + kt*16 + lm

    const float scale = 0.08838834764831845f;  // 1/sqrt(128)
    // per-wave row max (16-lane groups share a row set)
    #pragma unroll
    for (int r = 0; r < 4; ++r) {
        float v = fmaxf(fmaxf(sacc[0][r], sacc[1][r]), fmaxf(sacc[2][r], sacc[3][r]));
        #pragma unroll
        for (int o = 8; o >= 1; o >>= 1) v = fmaxf(v, __shfl_xor(v, o));
        if (lm == 0) red[wave][4 * lg + r] = v;
    }
    __syncthreads();
    float fm[4];
    #pragma unroll
    for (int r = 0; r < 4; ++r) {
        int q = 4 * lg + r;
        fm[r] = fmaxf(fmaxf(red[0][q], red[1][q]), fmaxf(red[2][q], red[3][q])) * scale;
    }
    // exp (unnormalized), row sums, P -> LDS (bf16, swizzled)
    #pragma unroll
    for (int r = 0; r < 4; ++r) {
        int q = 4 * lg + r;
        float s = 0.f;
        #pragma unroll
        for (int kt = 0; kt < 4; ++kt) {
            float e = __expf(sacc[kt][r] * scale - fm[r]);
            s += e;
            int key = wave * 64 + kt * 16 + lm;
            int idx = (q * 256 + key) ^ ((q & 7) << 3);
            P_lds[idx] = __float2bfloat16(e);
        }
        #pragma unroll
        for (int o = 8; o >= 1; o >>= 1) s += __shfl_xor(s, o);
        if (lm == 0) red2[wave][4 * lg + r] = s;
    }
    __syncthreads();

    int pbase = ((b * H + h) * TC + tc) * NREF + q0;
    if (tid < 16) {
        int q = tid;
        pm[pbase + q] = fmaxf(fmaxf(red[0][q], red[1][q]), fmaxf(red[2][q], red[3][q])) * scale;
        ps[pbase + q] = red2[0][q] + red2[1][q] + red2[2][q] + red2[3][q];
    }

    // ---- PV: wave owns v in [wave*32, wave*32+32), K = all 256 keys
    f32x4 oacc[2];
    oacc[0] = f32x4{0.f, 0.f, 0.f, 0.f};
    oacc[1] = f32x4{0.f, 0.f, 0.f, 0.f};
    const __hip_bfloat16* xb = xT + (size_t)b * LD * T_LEN + t0;
    #pragma unroll
    for (int ks = 0; ks < 8; ++ks) {              // k0 = ks*32
        int e0 = (lm * 256 + ks * 32 + 8 * lg) ^ ((lm & 7) << 3);
        bf16x8 af = *(const bf16x8*)&P_lds[e0];   // A: m=lm(q), k=8*lg+r
        #pragma unroll
        for (int nt = 0; nt < 2; ++nt) {
            int v = wave * 32 + nt * 16 + lm;
            bf16x8 bfr = *(const bf16x8*)(xb + (size_t)v * T_LEN + ks * 32 + 8 * lg);
            oacc[nt] = __builtin_amdgcn_mfma_f32_16x16x32_bf16(af, bfr, oacc[nt], 0, 0, 0);
        }
    }
    #pragma unroll
    for (int nt = 0; nt < 2; ++nt) {
        int v = wave * 32 + nt * 16 + lm;
        #pragma unroll
        for (int r = 0; r < 4; ++r) {
            int q = 4 * lg + r;
            pout[(size_t)(pbase + q) * LD + v] = oacc[nt][r];
        }
    }
}

// Combine 4 chunks + output projection. grid (32 qt4, 4 b), block 256
__global__ __launch_bounds__(256) void outc_kernel(const float* __restrict__ pm,
                                                   const float* __restrict__ ps,
                                                   const float* __restrict__ pout,
                                                   const float* __restrict__ Wo,
                                                   const float* __restrict__ bo,
                                                   float* __restrict__ out) {
    __shared__ float attl[4][516];
    int tid = threadIdx.x;
    int q0 = blockIdx.x * 4, b = blockIdx.y;
    for (int u = 0; u < 8; ++u) {
        int e = u * 256 + tid;
        int r = e >> 9, hv = e & 511;
        int h = hv >> 7, v = hv & 127;
        int pb = ((b * H + h) * TC) * NREF + q0 + r;
        float m0 = pm[pb], m1 = pm[pb + NREF], m2 = pm[pb + 2 * NREF], m3 = pm[pb + 3 * NREF];
        float m = fmaxf(fmaxf(m0, m1), fmaxf(m2, m3));
        float w0 = __expf(m0 - m), w1 = __expf(m1 - m), w2 = __expf(m2 - m), w3 = __expf(m3 - m);
        float den = w0 * ps[pb] + w1 * ps[pb + NREF] + w2 * ps[pb + 2 * NREF] + w3 * ps[pb + 3 * NREF];
        size_t po = (size_t)pb * LD + v;
        float num = w0 * pout[po]
                  + w1 * pout[po + (size_t)NREF * LD]
                  + w2 * pout[po + 2 * (size_t)NREF * LD]
                  + w3 * pout[po + 3 * (size_t)NREF * LD];
        attl[r][hv] = num / den;
    }
    __syncthreads();
    int j = tid & 127, rp = tid >> 7;
    float a0 = 0.f, a1 = 0.f;
    for (int i = 0; i < HLD; ++i) {
        float w = Wo[i * LD + j];
        a0 = fmaf(attl[rp][i], w, a0);
        a1 = fmaf(attl[rp + 2][i], w, a1);
    }
    float bb = bo[j];
    out[((size_t)b * NREF + q0 + rp) * LD + j]     = a0 + bb;
    out[((size_t)b * NREF + q0 + rp + 2) * LD + j] = a1 + bb;
}

extern "C" void kernel_launch(void* const* d_in, const int* in_sizes, int n_in,
                              void* d_out, int out_size, void* d_ws, size_t ws_size,
                              hipStream_t stream) {
    const float* ts   = (const float*)d_in[0];
    const int*   ys0  = (const int*)d_in[1];
    const int*   ys1  = (const int*)d_in[2];
    const float* x    = (const float*)d_in[3];
    const float* emb0 = (const float*)d_in[4];
    const float* emb1 = (const float*)d_in[5];
    const float* Wq   = (const float*)d_in[6];
    const float* bq   = (const float*)d_in[7];
    const float* Wk   = (const float*)d_in[8];
    const float* bk   = (const float*)d_in[9];
    const float* Wo   = (const float*)d_in[10];
    const float* bo   = (const float*)d_in[11];
    float* out = (float*)d_out;

    float* ws = (float*)d_ws;
    __hip_bfloat16* hq = (__hip_bfloat16*)ws;                      // 128*512 bf16  -> 32768 f
    __hip_bfloat16* hk = (__hip_bfloat16*)(ws + 32768);            // 4096*512 bf16 -> 1048576 f
    __hip_bfloat16* xT = (__hip_bfloat16*)(ws + 32768 + 1048576);  // 4*128*1024 bf16 -> 262144 f
    float* pm   = ws + 32768 + 1048576 + 262144;                   // 8192 f
    float* ps   = pm + 8192;                                       // 8192 f
    float* pout = ps + 8192;                                       // 1048576 f
    // total ~2.4M floats = 9.6 MB

    hipLaunchKernelGGL(hq_kernel, dim3(8, 4), dim3(256), 0, stream, emb0, emb1, Wq, bq, hq);
    hipLaunchKernelGGL(hk_kernel, dim3(256), dim3(512), 0, stream,
                       ts, ys0, ys1, emb0, emb1, Wk, bk, hk);
    hipLaunchKernelGGL(xt_kernel, dim3(16, 4), dim3(256), 0, stream, x, xT);
    hipLaunchKernelGGL(attn_part, dim3(8, 16, 4), dim3(256), 0, stream, hq, hk, xT, pm, ps, pout);
    hipLaunchKernelGGL(outc_kernel, dim3(32, 4), dim3(256), 0, stream, pm, ps, pout, Wo, bo, out);
}

// Round 4
// 47.648 us; speedup vs baseline: 3.8946x; 1.4877x over previous
//
#include <hip/hip_runtime.h>
#include <hip/hip_bf16.h>

#define N_B   4
#define T_LEN 1024
#define NREF  128
#define H     4
#define KQ    128
#define LD    128
#define HKQ   512
#define HLD   512
#define TC    4       // number of T chunks
#define TCHUNK 256    // keys per chunk

typedef __attribute__((ext_vector_type(8))) short bf16x8;   // 8 bf16 = 4 VGPRs
typedef __attribute__((ext_vector_type(4))) float f32x4;

union V8 { __hip_bfloat16 h[8]; bf16x8 v; };

__device__ __forceinline__ void sincos_pair(float t, int i, float* s, float* c) {
    // freq i in [0,32): angle = 48*t*exp(-2i*ln(10)/64)
    float div = __expf(-(float)(2 * i) * (2.302585093f / 64.0f));
    __sincosf(48.0f * t * div, s, c);
}

// pack_kernel: job-dispatched producer kernel.
//  jobs 0..7   : A-tensor  (h = j>>1, q-half = j&1): hq = qin@Wq_h + bq (MFMA),
//                then A_h = hq @ Wk_h^T (MFMA, B from global fp32->bf16)
//  jobs 8..71  : k_in build (64 rows each) bf16 [4096][128]
//  jobs 72..135: xT transpose x[b,t,v] f32 -> xT[b,v,t] bf16
__global__ __launch_bounds__(256) void pack_kernel(
    const float* __restrict__ ts, const int* __restrict__ ys0, const int* __restrict__ ys1,
    const float* __restrict__ x,
    const float* __restrict__ emb0, const float* __restrict__ emb1,
    const float* __restrict__ Wq, const float* __restrict__ bq,
    const float* __restrict__ Wk,
    __hip_bfloat16* __restrict__ A, __hip_bfloat16* __restrict__ kin,
    __hip_bfloat16* __restrict__ xT)
{
    __shared__ __align__(16) unsigned char smem[49152];
    int job = blockIdx.x;
    int tid = threadIdx.x;

    if (job < 8) {
        // ---------------- A job ----------------
        __hip_bfloat16* buf0 = (__hip_bfloat16*)smem;            // 64*128 bf16 = 16 KB (qin -> hq)
        __hip_bfloat16* wqt  = (__hip_bfloat16*)(smem + 16384);  // 128*128 bf16 = 32 KB (WqT)
        int h = job >> 1, qbase = (job & 1) * 64;

        // build qin (64 q rows x 128) bf16, XOR-swizzled rows
        for (int u = 0; u < 4; ++u) {
            int slot = u * 256 + tid;      // 0..1023
            int q = slot >> 4;             // local row 0..63
            int c0 = (slot & 15) * 8;
            V8 v;
            if (c0 < 64) {
                float t = (float)(qbase + q) / 127.0f;   // linspace(0,1,128)
                #pragma unroll
                for (int jj = 0; jj < 8; jj += 2) {
                    float s, c;
                    sincos_pair(t, (c0 + jj) >> 1, &s, &c);
                    v.h[jj] = __float2bfloat16(s);
                    v.h[jj + 1] = __float2bfloat16(c);
                }
            } else if (c0 < 96) {
                #pragma unroll
                for (int jj = 0; jj < 8; ++jj) v.h[jj] = __float2bfloat16(emb0[100 * 32 + (c0 - 64) + jj]);
            } else {
                #pragma unroll
                for (int jj = 0; jj < 8; ++jj) v.h[jj] = __float2bfloat16(emb1[50 * 32 + (c0 - 96) + jj]);
            }
            int idx = (q * 128 + c0) ^ ((q & 7) << 3);
            *(bf16x8*)&buf0[idx] = v.v;
        }
        // build WqT[d][i] bf16, swizzled (transpose of Wq_h)
        for (int u = 0; u < 16; ++u) {
            int s = u * 256 + tid;         // 0..4095
            int i = s >> 5;                // 0..127
            int d0 = (s & 31) * 4;
            float4 w = *(const float4*)&Wq[(size_t)i * HKQ + h * KQ + d0];
            float wv[4] = {w.x, w.y, w.z, w.w};
            #pragma unroll
            for (int jj = 0; jj < 4; ++jj) {
                int d = d0 + jj;
                wqt[(d * 128 + i) ^ ((d & 7) << 3)] = __float2bfloat16(wv[jj]);
            }
        }
        __syncthreads();

        int wave = tid >> 6, lane = tid & 63, lm = lane & 15, lg = lane >> 4;
        // stage 1: hq[64q x 128d] = qin @ WqT + bq; wave owns 16 q rows
        f32x4 acc[8];
        #pragma unroll
        for (int dt = 0; dt < 8; ++dt) acc[dt] = f32x4{0.f, 0.f, 0.f, 0.f};
        #pragma unroll
        for (int ks = 0; ks < 4; ++ks) {
            int q = wave * 16 + lm;
            bf16x8 af = *(bf16x8*)&buf0[(q * 128 + ks * 32 + 8 * lg) ^ ((q & 7) << 3)];
            #pragma unroll
            for (int dt = 0; dt < 8; ++dt) {
                int d = dt * 16 + lm;
                bf16x8 bfr = *(bf16x8*)&wqt[(d * 128 + ks * 32 + 8 * lg) ^ ((d & 7) << 3)];
                acc[dt] = __builtin_amdgcn_mfma_f32_16x16x32_bf16(af, bfr, acc[dt], 0, 0, 0);
            }
        }
        __syncthreads();   // qin fully consumed
        // hq (+bias) -> buf0, swizzled
        #pragma unroll
        for (int dt = 0; dt < 8; ++dt) {
            int d = dt * 16 + lm;
            float bb = bq[h * KQ + d];
            #pragma unroll
            for (int r = 0; r < 4; ++r) {
                int q = wave * 16 + 4 * lg + r;
                buf0[(q * 128 + d) ^ ((q & 7) << 3)] = __float2bfloat16(acc[dt][r] + bb);
            }
        }
        __syncthreads();
        // stage 2: A[64q x 128i] = hq @ Wk_h^T (contract d); B rows from global fp32
        f32x4 acc2[8];
        #pragma unroll
        for (int it = 0; it < 8; ++it) acc2[it] = f32x4{0.f, 0.f, 0.f, 0.f};
        #pragma unroll
        for (int ks = 0; ks < 4; ++ks) {
            int q = wave * 16 + lm;
            bf16x8 af = *(bf16x8*)&buf0[(q * 128 + ks * 32 + 8 * lg) ^ ((q & 7) << 3)];
            #pragma unroll
            for (int it = 0; it < 8; ++it) {
                int i2 = it * 16 + lm;
                const float* wkp = &Wk[(size_t)i2 * HKQ + h * KQ + ks * 32 + 8 * lg];
                float4 wa = *(const float4*)wkp;
                float4 wb = *(const float4*)(wkp + 4);
                V8 bv;
                bv.h[0] = __float2bfloat16(wa.x); bv.h[1] = __float2bfloat16(wa.y);
                bv.h[2] = __float2bfloat16(wa.z); bv.h[3] = __float2bfloat16(wa.w);
                bv.h[4] = __float2bfloat16(wb.x); bv.h[5] = __float2bfloat16(wb.y);
                bv.h[6] = __float2bfloat16(wb.z); bv.h[7] = __float2bfloat16(wb.w);
                acc2[it] = __builtin_amdgcn_mfma_f32_16x16x32_bf16(af, bv.v, acc2[it], 0, 0, 0);
            }
        }
        // store A: [h][q][i] bf16
        #pragma unroll
        for (int it = 0; it < 8; ++it) {
            int i2 = it * 16 + lm;
            #pragma unroll
            for (int r = 0; r < 4; ++r) {
                int q = qbase + wave * 16 + 4 * lg + r;
                A[((size_t)h * NREF + q) * KQ + i2] = __float2bfloat16(acc2[it][r]);
            }
        }
    } else if (job < 72) {
        // ---------------- k_in job ----------------
        int row0 = (job - 8) * 64;
        for (int u = 0; u < 4; ++u) {
            int slot = u * 256 + tid;     // 0..1023
            int r = slot >> 4;            // 0..63
            int c0 = (slot & 15) * 8;
            int bt = row0 + r;
            V8 v;
            if (c0 < 64) {
                float t = ts[bt];
                #pragma unroll
                for (int jj = 0; jj < 8; jj += 2) {
                    float s, c;
                    sincos_pair(t, (c0 + jj) >> 1, &s, &c);
                    v.h[jj] = __float2bfloat16(s);
                    v.h[jj + 1] = __float2bfloat16(c);
                }
            } else if (c0 < 96) {
                int y = ys0[bt];
                #pragma unroll
                for (int jj = 0; jj < 8; ++jj) v.h[jj] = __float2bfloat16(emb0[y * 32 + (c0 - 64) + jj]);
            } else {
                int y = ys1[bt];
                #pragma unroll
                for (int jj = 0; jj < 8; ++jj) v.h[jj] = __float2bfloat16(emb1[y * 32 + (c0 - 96) + jj]);
            }
            *(bf16x8*)&kin[(size_t)bt * KQ + c0] = v.v;
        }
    } else {
        // ---------------- xT job ----------------
        __hip_bfloat16 (*tile)[136] = (__hip_bfloat16(*)[136])smem;   // 64*136*2 = 17.4 KB
        int jb = job - 72;
        int b = jb >> 4, t0 = (jb & 15) * 64;
        for (int e = tid; e < 64 * 32; e += 256) {
            int tt = e >> 5, v4 = e & 31;
            float4 xv = *(const float4*)&x[((size_t)(b * T_LEN + t0 + tt)) * LD + v4 * 4];
            tile[tt][v4 * 4 + 0] = __float2bfloat16(xv.x);
            tile[tt][v4 * 4 + 1] = __float2bfloat16(xv.y);
            tile[tt][v4 * 4 + 2] = __float2bfloat16(xv.z);
            tile[tt][v4 * 4 + 3] = __float2bfloat16(xv.w);
        }
        __syncthreads();
        int v = tid >> 1, th = (tid & 1) * 32;
        for (int i = 0; i < 32; i += 4) {
            ushort4 u;
            u.x = *(unsigned short*)&tile[th + i + 0][v];
            u.y = *(unsigned short*)&tile[th + i + 1][v];
            u.z = *(unsigned short*)&tile[th + i + 2][v];
            u.w = *(unsigned short*)&tile[th + i + 3][v];
            *(ushort4*)&xT[((size_t)b * LD + v) * T_LEN + t0 + th + i] = u;
        }
    }
}

// MFMA partial attention: one (16q, h, 256-key chunk, b) per 4-wave block.
// scores = A_h[q,:] . k_in[t,:]   (hk eliminated; bk cancels in softmax)
// grid (8 qt, 16 = h + 4*tc, 4 b), block 256
__global__ __launch_bounds__(256) void attn_part(const __hip_bfloat16* __restrict__ A,
                                                 const __hip_bfloat16* __restrict__ kin,
                                                 const __hip_bfloat16* __restrict__ xT,
                                                 float* __restrict__ pm,
                                                 float* __restrict__ ps,
                                                 float* __restrict__ pout) {
    __shared__ __hip_bfloat16 P_lds[16 * 256];   // XOR-swizzled: elem ^= (q&7)<<3
    __shared__ float red[4][16], red2[4][16];

    int tid = threadIdx.x;
    int wave = tid >> 6, lane = tid & 63;
    int lm = lane & 15, lg = lane >> 4;
    int qt = blockIdx.x, h = blockIdx.y & 3, tc = blockIdx.y >> 2, b = blockIdx.z;
    int q0 = qt * 16, t0 = tc * TCHUNK;

    // ---- scores: wave owns keys [wave*64, wave*64+64), 4 ktiles of 16
    f32x4 sacc[4];
    #pragma unroll
    for (int kt = 0; kt < 4; ++kt) sacc[kt] = f32x4{0.f, 0.f, 0.f, 0.f};

    const __hip_bfloat16* aptr = A + ((size_t)h * NREF + q0 + lm) * KQ + lg * 8;
    const __hip_bfloat16* bptr = kin + (size_t)(b * T_LEN + t0 + wave * 64 + lm) * KQ + lg * 8;
    #pragma unroll
    for (int ks = 0; ks < 4; ++ks) {              // k0 = ks*32
        bf16x8 af = *(const bf16x8*)(aptr + ks * 32);
        #pragma unroll
        for (int kt = 0; kt < 4; ++kt) {
            bf16x8 bfr = *(const bf16x8*)(bptr + (size_t)kt * 16 * KQ + ks * 32);
            sacc[kt] = __builtin_amdgcn_mfma_f32_16x16x32_bf16(af, bfr, sacc[kt], 0, 0, 0);
        }
    }
    // D layout: reg r -> row q = 4*lg + r, col key = wave*64 + kt*16 + lm

    const float scale = 0.08838834764831845f;  // 1/sqrt(128)
    #pragma unroll
    for (int r = 0; r < 4; ++r) {
        float v = fmaxf(fmaxf(sacc[0][r], sacc[1][r]), fmaxf(sacc[2][r], sacc[3][r]));
        #pragma unroll
        for (int o = 8; o >= 1; o >>= 1) v = fmaxf(v, __shfl_xor(v, o));
        if (lm == 0) red[wave][4 * lg + r] = v;
    }
    __syncthreads();
    float fm[4];
    #pragma unroll
    for (int r = 0; r < 4; ++r) {
        int q = 4 * lg + r;
        fm[r] = fmaxf(fmaxf(red[0][q], red[1][q]), fmaxf(red[2][q], red[3][q])) * scale;
    }
    #pragma unroll
    for (int r = 0; r < 4; ++r) {
        int q = 4 * lg + r;
        float s = 0.f;
        #pragma unroll
        for (int kt = 0; kt < 4; ++kt) {
            float e = __expf(sacc[kt][r] * scale - fm[r]);
            s += e;
            int key = wave * 64 + kt * 16 + lm;
            int idx = (q * 256 + key) ^ ((q & 7) << 3);
            P_lds[idx] = __float2bfloat16(e);
        }
        #pragma unroll
        for (int o = 8; o >= 1; o >>= 1) s += __shfl_xor(s, o);
        if (lm == 0) red2[wave][4 * lg + r] = s;
    }
    __syncthreads();

    int pbase = ((b * H + h) * TC + tc) * NREF + q0;
    if (tid < 16) {
        int q = tid;
        pm[pbase + q] = fmaxf(fmaxf(red[0][q], red[1][q]), fmaxf(red[2][q], red[3][q])) * scale;
        ps[pbase + q] = red2[0][q] + red2[1][q] + red2[2][q] + red2[3][q];
    }

    // ---- PV: wave owns v in [wave*32, wave*32+32), K = all 256 keys
    f32x4 oacc[2];
    oacc[0] = f32x4{0.f, 0.f, 0.f, 0.f};
    oacc[1] = f32x4{0.f, 0.f, 0.f, 0.f};
    const __hip_bfloat16* xb = xT + (size_t)b * LD * T_LEN + t0;
    #pragma unroll
    for (int ks = 0; ks < 8; ++ks) {              // k0 = ks*32
        int e0 = (lm * 256 + ks * 32 + 8 * lg) ^ ((lm & 7) << 3);
        bf16x8 af = *(const bf16x8*)&P_lds[e0];   // A: m=lm(q), k=8*lg+r
        #pragma unroll
        for (int nt = 0; nt < 2; ++nt) {
            int v = wave * 32 + nt * 16 + lm;
            bf16x8 bfr = *(const bf16x8*)(xb + (size_t)v * T_LEN + ks * 32 + 8 * lg);
            oacc[nt] = __builtin_amdgcn_mfma_f32_16x16x32_bf16(af, bfr, oacc[nt], 0, 0, 0);
        }
    }
    #pragma unroll
    for (int nt = 0; nt < 2; ++nt) {
        int v = wave * 32 + nt * 16 + lm;
        #pragma unroll
        for (int r = 0; r < 4; ++r) {
            int q = 4 * lg + r;
            pout[(size_t)(pbase + q) * LD + v] = oacc[nt][r];
        }
    }
}

// Combine 4 chunks + output projection. grid (32 qt4, 4 b), block 256
__global__ __launch_bounds__(256) void outc_kernel(const float* __restrict__ pm,
                                                   const float* __restrict__ ps,
                                                   const float* __restrict__ pout,
                                                   const float* __restrict__ Wo,
                                                   const float* __restrict__ bo,
                                                   float* __restrict__ out) {
    __shared__ float attl[4][516];
    int tid = threadIdx.x;
    int q0 = blockIdx.x * 4, b = blockIdx.y;
    for (int u = 0; u < 8; ++u) {
        int e = u * 256 + tid;
        int r = e >> 9, hv = e & 511;
        int h = hv >> 7, v = hv & 127;
        int pb = ((b * H + h) * TC) * NREF + q0 + r;
        float m0 = pm[pb], m1 = pm[pb + NREF], m2 = pm[pb + 2 * NREF], m3 = pm[pb + 3 * NREF];
        float m = fmaxf(fmaxf(m0, m1), fmaxf(m2, m3));
        float w0 = __expf(m0 - m), w1 = __expf(m1 - m), w2 = __expf(m2 - m), w3 = __expf(m3 - m);
        float den = w0 * ps[pb] + w1 * ps[pb + NREF] + w2 * ps[pb + 2 * NREF] + w3 * ps[pb + 3 * NREF];
        size_t po = (size_t)pb * LD + v;
        float num = w0 * pout[po]
                  + w1 * pout[po + (size_t)NREF * LD]
                  + w2 * pout[po + 2 * (size_t)NREF * LD]
                  + w3 * pout[po + 3 * (size_t)NREF * LD];
        attl[r][hv] = num / den;
    }
    __syncthreads();
    int j = tid & 127, rp = tid >> 7;
    float a0 = 0.f, a1 = 0.f;
    for (int i = 0; i < HLD; ++i) {
        float w = Wo[i * LD + j];
        a0 = fmaf(attl[rp][i], w, a0);
        a1 = fmaf(attl[rp + 2][i], w, a1);
    }
    float bb = bo[j];
    out[((size_t)b * NREF + q0 + rp) * LD + j]     = a0 + bb;
    out[((size_t)b * NREF + q0 + rp + 2) * LD + j] = a1 + bb;
}

extern "C" void kernel_launch(void* const* d_in, const int* in_sizes, int n_in,
                              void* d_out, int out_size, void* d_ws, size_t ws_size,
                              hipStream_t stream) {
    const float* ts   = (const float*)d_in[0];
    const int*   ys0  = (const int*)d_in[1];
    const int*   ys1  = (const int*)d_in[2];
    const float* x    = (const float*)d_in[3];
    const float* emb0 = (const float*)d_in[4];
    const float* emb1 = (const float*)d_in[5];
    const float* Wq   = (const float*)d_in[6];
    const float* bq   = (const float*)d_in[7];
    const float* Wk   = (const float*)d_in[8];
    // d_in[9] = bk: cancels exactly in softmax (constant per (h,q) row) — unused
    const float* Wo   = (const float*)d_in[10];
    const float* bo   = (const float*)d_in[11];
    float* out = (float*)d_out;

    float* ws = (float*)d_ws;
    __hip_bfloat16* A   = (__hip_bfloat16*)ws;                     // 4*128*128 bf16 -> 32768 f
    __hip_bfloat16* kin = (__hip_bfloat16*)(ws + 32768);           // 4096*128 bf16  -> 262144 f
    __hip_bfloat16* xT  = (__hip_bfloat16*)(ws + 32768 + 262144);  // 4*128*1024 bf16 -> 262144 f
    float* pm   = ws + 32768 + 262144 + 262144;                    // 8192 f
    float* ps   = pm + 8192;                                       // 8192 f
    float* pout = ps + 8192;                                       // 1048576 f
    // total ~1.62M floats = 6.5 MB

    hipLaunchKernelGGL(pack_kernel, dim3(136), dim3(256), 0, stream,
                       ts, ys0, ys1, x, emb0, emb1, Wq, bq, Wk, A, kin, xT);
    hipLaunchKernelGGL(attn_part, dim3(8, 16, 4), dim3(256), 0, stream, A, kin, xT, pm, ps, pout);
    hipLaunchKernelGGL(outc_kernel, dim3(32, 4), dim3(256), 0, stream, pm, ps, pout, Wo, bo, out);
}